// Round 1
// baseline (568.454 us; speedup 1.0000x reference)
//
#include <hip/hip_runtime.h>
#include <hip/hip_bf16.h>

// KronLinear: out = x @ (sum_r kron(a_r, b_r)) + bias
// M=8192 tokens, K=4096=(i,k_b), N=4096=(j,l), RANK=64.
// Strategy: materialize W^T in bf16 (packed for MFMA staging), then m97-style
// bf16 MFMA GEMM (128x128 tile, BK=32, global_load_lds width 16).

#define M_DIM 8192
#define N_DIM 4096
#define K_DIM 4096
#define KT_COUNT 128   // K_DIM / 32

typedef __attribute__((ext_vector_type(8))) short short8;
typedef __attribute__((ext_vector_type(4))) float floatx4;

typedef __attribute__((address_space(1))) void gvoid_t;
typedef __attribute__((address_space(3))) void lvoid_t;

static __device__ __forceinline__ void gl_lds16(const void* g, const void* l) {
  // LDS dest is wave-uniform base; HW adds lane*16. Integer detours make the
  // addrspace casts unconditionally legal.
  __builtin_amdgcn_global_load_lds((gvoid_t*)(unsigned long long)g,
                                   (lvoid_t*)(unsigned int)(unsigned long long)l,
                                   16, 0, 0);
}

static __device__ __forceinline__ unsigned short f2bf(float f) {
  unsigned int u = __builtin_bit_cast(unsigned int, f);
  u = (u + 0x7fffu + ((u >> 16) & 1u)) >> 16;  // RNE
  return (unsigned short)u;
}

// ---------------------------------------------------------------------------
// Kernel 1: convert x (fp32, row-major 8192x4096) -> packed bf16 blobs.
// Blob (M0, kt) = 128 rows x 32 k, 4096 bf16 = 8KB, contiguous.
// Chunk p = c*128 + mm (c = k-octet 0..3, mm = row%128) holds
// x[M0*128+mm][kt*32 + c*8 .. +7] as 8 bf16 (16B).
// ---------------------------------------------------------------------------
__global__ __launch_bounds__(256) void pack_x_kernel(
    const float* __restrict__ x, unsigned short* __restrict__ Xp) {
  __shared__ float xs[128 * 33];  // pad 33: conflict-free scalar access
  const int kt = blockIdx.x;   // 0..127
  const int M0 = blockIdx.y;   // 0..63
  const int t = threadIdx.x;

  {  // load 128 rows x 32 floats, coalesced (2 threads per row, 64B each)
    const int row = t >> 1;
    const int half = t & 1;
    const float* src = x + (size_t)(M0 * 128 + row) * K_DIM + kt * 32 + half * 16;
    float v[16];
#pragma unroll
    for (int w = 0; w < 4; ++w) {
      float4 vv = ((const float4*)src)[w];
      v[w * 4 + 0] = vv.x; v[w * 4 + 1] = vv.y;
      v[w * 4 + 2] = vv.z; v[w * 4 + 3] = vv.w;
    }
#pragma unroll
    for (int e = 0; e < 16; ++e) xs[row * 33 + half * 16 + e] = v[e];
  }
  __syncthreads();

  unsigned short* dst = Xp + (size_t)(M0 * KT_COUNT + kt) * 4096;
#pragma unroll
  for (int q = 0; q < 2; ++q) {
    const int p = q * 256 + t;
    const int c = p >> 7, mm = p & 127;
    short8 o;
#pragma unroll
    for (int j = 0; j < 8; ++j) o[j] = (short)f2bf(xs[mm * 33 + c * 8 + j]);
    *(short8*)(dst + p * 8) = o;  // consecutive t -> consecutive 16B: coalesced
  }
}

// ---------------------------------------------------------------------------
// Kernel 2: build W^T packed.  wT[n=(j*64+l)][kk=(i*64+k_b)] = sum_r a[r,i,j]*b[r,k_b,l]
// Block = (i fixed, j0..j0+15) x (k0..k0+7).  Thread t: l = t&63, jj = t>>6.
// acc[4 j][8 k_b] per thread.  Writes land as full 16B chunks in packed blobs.
// ---------------------------------------------------------------------------
__global__ __launch_bounds__(256) void build_w_kernel(
    const float* __restrict__ a, const float* __restrict__ b,
    unsigned short* __restrict__ Wp) {
  __shared__ float as_lds[1024];  // [r][16 j], r-major
  const int rg = blockIdx.x;          // 0..255
  const int i = rg >> 2;
  const int j0 = (rg & 3) * 16;
  const int k0 = blockIdx.y * 8;      // 0..56
  const int t = threadIdx.x;

  {  // load a[r, i, j0..j0+15] for all r: 1024 floats
    const int r = t >> 2, jq = t & 3;
    float4 v = ((const float4*)(a + (size_t)r * 4096 + i * 64 + j0))[jq];
    ((float4*)as_lds)[r * 4 + jq] = v;
  }
  __syncthreads();

  const int l = t & 63;
  const int jj = t >> 6;  // 0..3
  float acc[4][8];
#pragma unroll
  for (int jp = 0; jp < 4; ++jp)
#pragma unroll
    for (int kb = 0; kb < 8; ++kb) acc[jp][kb] = 0.f;

  const float* bb = b + k0 * 64 + l;  // b[r*4096 + (k0+kb)*64 + l]
  for (int r = 0; r < 64; ++r) {
    float4 aj = ((const float4*)as_lds)[r * 4 + jj];  // a[r,i,j0+jj*4 ..+3]
    float bv[8];
#pragma unroll
    for (int kb = 0; kb < 8; ++kb) bv[kb] = bb[(size_t)r * 4096 + kb * 64];
    const float av[4] = {aj.x, aj.y, aj.z, aj.w};
#pragma unroll
    for (int jp = 0; jp < 4; ++jp)
#pragma unroll
      for (int kb = 0; kb < 8; ++kb)
        acc[jp][kb] = fmaf(av[jp], bv[kb], acc[jp][kb]);
  }

  // write: kk = i*64 + k0 + kb -> one chunk per (n, 8 kb's)
  const int kt = (i * 64 + k0) >> 5;
  const int c = (k0 & 31) >> 3;
#pragma unroll
  for (int jp = 0; jp < 4; ++jp) {
    const int j = j0 + jj * 4 + jp;
    const int n = j * 64 + l;
    const int blob = (n >> 7) * KT_COUNT + kt;
    const int pos = c * 128 + (n & 127);
    short8 o;
#pragma unroll
    for (int kb = 0; kb < 8; ++kb) o[kb] = (short)f2bf(acc[jp][kb]);
    *(short8*)(Wp + (size_t)blob * 4096 + pos * 8) = o;
  }
}

// ---------------------------------------------------------------------------
// Kernel 3: C = Xp @ Wp^T + bias.  128x128 tile, BK=32, 4 waves (2x2),
// each wave 4x4 tiles of 16x16x32 bf16 MFMA.  m97 2-barrier K-loop.
// ---------------------------------------------------------------------------
__global__ __launch_bounds__(256) void gemm_kernel(
    const unsigned short* __restrict__ Xp, const unsigned short* __restrict__ Wp,
    const float* __restrict__ bias, float* __restrict__ out) {
  __shared__ short8 As[512];  // 8KB: chunk idx = c*128 + m
  __shared__ short8 Bs[512];  // 8KB: chunk idx = c*128 + n

  const int N0 = blockIdx.x;  // 0..31
  const int M0 = blockIdx.y;  // 0..63
  const int t = threadIdx.x;
  const int wave = t >> 6, lane = t & 63;
  const int l16 = lane & 15, quad = lane >> 4;
  const int wm = wave & 1, wn = wave >> 1;

  floatx4 acc[4][4];
#pragma unroll
  for (int mt = 0; mt < 4; ++mt)
#pragma unroll
    for (int nt = 0; nt < 4; ++nt) acc[mt][nt] = (floatx4){0.f, 0.f, 0.f, 0.f};

  const unsigned short* pa = Xp + (size_t)M0 * KT_COUNT * 4096 + (size_t)t * 8;
  const unsigned short* pb = Wp + (size_t)N0 * KT_COUNT * 4096 + (size_t)t * 8;
  const short8* lA0 = As + wave * 64;        // wave-uniform LDS bases
  const short8* lA1 = As + 256 + wave * 64;
  const short8* lB0 = Bs + wave * 64;
  const short8* lB1 = Bs + 256 + wave * 64;

  for (int kt = 0; kt < KT_COUNT; ++kt) {
    __syncthreads();  // previous tile's compute done
    gl_lds16(pa, lA0);
    gl_lds16(pa + 2048, lA1);
    gl_lds16(pb, lB0);
    gl_lds16(pb + 2048, lB1);
    pa += 4096;
    pb += 4096;
    __syncthreads();  // forces vmcnt(0): staging complete

    short8 af[4], bf[4];
#pragma unroll
    for (int mt = 0; mt < 4; ++mt)
      af[mt] = As[quad * 128 + wm * 64 + mt * 16 + l16];
#pragma unroll
    for (int nt = 0; nt < 4; ++nt)
      bf[nt] = Bs[quad * 128 + wn * 64 + nt * 16 + l16];
#pragma unroll
    for (int mt = 0; mt < 4; ++mt)
#pragma unroll
      for (int nt = 0; nt < 4; ++nt)
        acc[mt][nt] = __builtin_amdgcn_mfma_f32_16x16x32_bf16(
            af[mt], bf[nt], acc[mt][nt], 0, 0, 0);
  }

  const int col_base = N0 * 128 + wn * 64;
  const int row_base = M0 * 128 + wm * 64;
#pragma unroll
  for (int nt = 0; nt < 4; ++nt) {
    const int col = col_base + nt * 16 + l16;
    const float bv = bias[col];
#pragma unroll
    for (int mt = 0; mt < 4; ++mt) {
      floatx4 v = acc[mt][nt];
#pragma unroll
      for (int r4 = 0; r4 < 4; ++r4) {
        const int row = row_base + mt * 16 + quad * 4 + r4;
        out[(size_t)row * N_DIM + col] = v[r4] + bv;
      }
    }
  }
}

extern "C" void kernel_launch(void* const* d_in, const int* in_sizes, int n_in,
                              void* d_out, int out_size, void* d_ws, size_t ws_size,
                              hipStream_t stream) {
  const float* x = (const float*)d_in[0];     // 8192*4096
  const float* a = (const float*)d_in[1];     // 64*64*64 (r,i,j)
  const float* b = (const float*)d_in[2];     // 64*64*64 (r,k,l)
  const float* bias = (const float*)d_in[3];  // 4096
  float* out = (float*)d_out;

  unsigned short* Xp = (unsigned short*)d_ws;                       // 67MB
  unsigned short* Wp = Xp + (size_t)M_DIM * K_DIM;                  // 33.5MB

  pack_x_kernel<<<dim3(KT_COUNT, M_DIM / 128), 256, 0, stream>>>(x, Xp);
  build_w_kernel<<<dim3(256, 8), 256, 0, stream>>>(a, b, Wp);
  gemm_kernel<<<dim3(N_DIM / 128, M_DIM / 128), 256, 0, stream>>>(Xp, Wp, bias, out);
}

// Round 2
// 505.950 us; speedup vs baseline: 1.1235x; 1.1235x over previous
//
#include <hip/hip_runtime.h>
#include <hip/hip_bf16.h>

// KronLinear: out = x @ (sum_r kron(a_r, b_r)) + bias
// M=8192 tokens, K=4096=(i,k_b), N=4096=(j,l), RANK=64.
// R1->R2: fused prep kernel (build_w blocks first, overlap with pack_x);
// XCD-aware swizzle in gemm so each XCD's L2 pins a 4MB Wp slice.

#define M_DIM 8192
#define N_DIM 4096
#define K_DIM 4096
#define KT_COUNT 128   // K_DIM / 32

typedef __attribute__((ext_vector_type(8))) short short8;
typedef __attribute__((ext_vector_type(4))) float floatx4;

typedef __attribute__((address_space(1))) void gvoid_t;
typedef __attribute__((address_space(3))) void lvoid_t;

static __device__ __forceinline__ void gl_lds16(const void* g, const void* l) {
  __builtin_amdgcn_global_load_lds((gvoid_t*)(unsigned long long)g,
                                   (lvoid_t*)(unsigned int)(unsigned long long)l,
                                   16, 0, 0);
}

static __device__ __forceinline__ unsigned short f2bf(float f) {
  unsigned int u = __builtin_bit_cast(unsigned int, f);
  u = (u + 0x7fffu + ((u >> 16) & 1u)) >> 16;  // RNE
  return (unsigned short)u;
}

// ---------------------------------------------------------------------------
// Fused prep: blocks [0,2048) build W^T packed; blocks [2048,10240) pack x.
// build_w first in dispatch order: latency-bound, overlaps pack's BW streaming.
//
// Packed blob (T0, kt) = 128 rows x 32 k: chunk p = c*128 + mm holds
// row (T0*128+mm), k = kt*32 + c*8 .. +7, as 8 bf16 (16B). Identical layout
// for Xp (rows = tokens) and Wp (rows = n = j*64+l).
// ---------------------------------------------------------------------------
__global__ __launch_bounds__(256) void prep_kernel(
    const float* __restrict__ x, const float* __restrict__ a,
    const float* __restrict__ b, unsigned short* __restrict__ Xp,
    unsigned short* __restrict__ Wp) {
  __shared__ float lds[128 * 33];
  const int bid = blockIdx.x;
  const int t = threadIdx.x;

  if (bid < 2048) {
    // ---- build W^T: wT[n=(j*64+l)][i*64+k_b] = sum_r a[r,i,j]*b[r,k_b,l]
    const int rg = bid & 255;
    const int i = rg >> 2;
    const int j0 = (rg & 3) * 16;
    const int k0 = (bid >> 8) * 8;  // 0..56

    {  // stage a[r, i, j0..j0+15] for all r: 1024 floats, [r][16j]
      const int r = t >> 2, jq = t & 3;
      float4 v = ((const float4*)(a + (size_t)r * 4096 + i * 64 + j0))[jq];
      ((float4*)lds)[r * 4 + jq] = v;
    }
    __syncthreads();

    const int l = t & 63;
    const int jj = t >> 6;  // 0..3
    float acc[4][8];
#pragma unroll
    for (int jp = 0; jp < 4; ++jp)
#pragma unroll
      for (int kb = 0; kb < 8; ++kb) acc[jp][kb] = 0.f;

    const float* bb = b + k0 * 64 + l;
#pragma unroll 4
    for (int r = 0; r < 64; ++r) {
      float4 aj = ((const float4*)lds)[r * 4 + jj];
      float bv[8];
#pragma unroll
      for (int kb = 0; kb < 8; ++kb) bv[kb] = bb[(size_t)r * 4096 + kb * 64];
      const float av[4] = {aj.x, aj.y, aj.z, aj.w};
#pragma unroll
      for (int jp = 0; jp < 4; ++jp)
#pragma unroll
        for (int kb = 0; kb < 8; ++kb)
          acc[jp][kb] = fmaf(av[jp], bv[kb], acc[jp][kb]);
    }

    const int kt = (i * 64 + k0) >> 5;
    const int c = (k0 & 31) >> 3;
#pragma unroll
    for (int jp = 0; jp < 4; ++jp) {
      const int j = j0 + jj * 4 + jp;
      const int n = j * 64 + l;
      const int blob = (n >> 7) * KT_COUNT + kt;
      const int pos = c * 128 + (n & 127);
      short8 o;
#pragma unroll
      for (int kb = 0; kb < 8; ++kb) o[kb] = (short)f2bf(acc[jp][kb]);
      *(short8*)(Wp + (size_t)blob * 4096 + pos * 8) = o;
    }
  } else {
    // ---- pack x
    const int pid = bid - 2048;
    const int kt = pid & 127;
    const int M0 = pid >> 7;

    {  // load 128 rows x 32 floats, coalesced (2 threads/row, 64B each)
      const int row = t >> 1;
      const int half = t & 1;
      const float* src = x + (size_t)(M0 * 128 + row) * K_DIM + kt * 32 + half * 16;
      float v[16];
#pragma unroll
      for (int w = 0; w < 4; ++w) {
        float4 vv = ((const float4*)src)[w];
        v[w * 4 + 0] = vv.x; v[w * 4 + 1] = vv.y;
        v[w * 4 + 2] = vv.z; v[w * 4 + 3] = vv.w;
      }
#pragma unroll
      for (int e = 0; e < 16; ++e) lds[row * 33 + half * 16 + e] = v[e];
    }
    __syncthreads();

    unsigned short* dst = Xp + (size_t)(M0 * KT_COUNT + kt) * 4096;
#pragma unroll
    for (int q = 0; q < 2; ++q) {
      const int p = q * 256 + t;
      const int c = p >> 7, mm = p & 127;
      short8 o;
#pragma unroll
      for (int j = 0; j < 8; ++j) o[j] = (short)f2bf(lds[mm * 33 + c * 8 + j]);
      *(short8*)(dst + p * 8) = o;
    }
  }
}

// ---------------------------------------------------------------------------
// GEMM: C = Xp @ Wp^T + bias.  128x128 tile, BK=32, 4 waves (2x2),
// each wave 4x4 tiles of 16x16x32 bf16 MFMA.  m97 2-barrier K-loop.
// XCD swizzle: bid%8 -> XCD owns N0 in [xcd*4, xcd*4+4) (4MB Wp = one L2),
// M-major within XCD so same-M0 blocks are concurrent.
// ---------------------------------------------------------------------------
__global__ __launch_bounds__(256) void gemm_kernel(
    const unsigned short* __restrict__ Xp, const unsigned short* __restrict__ Wp,
    const float* __restrict__ bias, float* __restrict__ out) {
  __shared__ short8 As[512];  // 8KB: chunk idx = c*128 + m
  __shared__ short8 Bs[512];  // 8KB: chunk idx = c*128 + n

  const int bid = blockIdx.x;
  const int xcd = bid & 7;
  const int pos = bid >> 3;          // 0..255
  const int N0 = xcd * 4 + (pos & 3);  // 0..31
  const int M0 = pos >> 2;             // 0..63

  const int t = threadIdx.x;
  const int wave = t >> 6, lane = t & 63;
  const int l16 = lane & 15, quad = lane >> 4;
  const int wm = wave & 1, wn = wave >> 1;

  floatx4 acc[4][4];
#pragma unroll
  for (int mt = 0; mt < 4; ++mt)
#pragma unroll
    for (int nt = 0; nt < 4; ++nt) acc[mt][nt] = (floatx4){0.f, 0.f, 0.f, 0.f};

  const unsigned short* pa = Xp + (size_t)M0 * KT_COUNT * 4096 + (size_t)t * 8;
  const unsigned short* pb = Wp + (size_t)N0 * KT_COUNT * 4096 + (size_t)t * 8;
  const short8* lA0 = As + wave * 64;
  const short8* lA1 = As + 256 + wave * 64;
  const short8* lB0 = Bs + wave * 64;
  const short8* lB1 = Bs + 256 + wave * 64;

  for (int kt = 0; kt < KT_COUNT; ++kt) {
    __syncthreads();
    gl_lds16(pa, lA0);
    gl_lds16(pa + 2048, lA1);
    gl_lds16(pb, lB0);
    gl_lds16(pb + 2048, lB1);
    pa += 4096;
    pb += 4096;
    __syncthreads();

    short8 af[4], bf[4];
#pragma unroll
    for (int mt = 0; mt < 4; ++mt)
      af[mt] = As[quad * 128 + wm * 64 + mt * 16 + l16];
#pragma unroll
    for (int nt = 0; nt < 4; ++nt)
      bf[nt] = Bs[quad * 128 + wn * 64 + nt * 16 + l16];
#pragma unroll
    for (int mt = 0; mt < 4; ++mt)
#pragma unroll
      for (int nt = 0; nt < 4; ++nt)
        acc[mt][nt] = __builtin_amdgcn_mfma_f32_16x16x32_bf16(
            af[mt], bf[nt], acc[mt][nt], 0, 0, 0);
  }

  const int col_base = N0 * 128 + wn * 64;
  const int row_base = M0 * 128 + wm * 64;
#pragma unroll
  for (int nt = 0; nt < 4; ++nt) {
    const int col = col_base + nt * 16 + l16;
    const float bv = bias[col];
#pragma unroll
    for (int mt = 0; mt < 4; ++mt) {
      floatx4 v = acc[mt][nt];
#pragma unroll
      for (int r4 = 0; r4 < 4; ++r4) {
        const int row = row_base + mt * 16 + quad * 4 + r4;
        out[(size_t)row * N_DIM + col] = v[r4] + bv;
      }
    }
  }
}

extern "C" void kernel_launch(void* const* d_in, const int* in_sizes, int n_in,
                              void* d_out, int out_size, void* d_ws, size_t ws_size,
                              hipStream_t stream) {
  const float* x = (const float*)d_in[0];     // 8192*4096
  const float* a = (const float*)d_in[1];     // 64*64*64 (r,i,j)
  const float* b = (const float*)d_in[2];     // 64*64*64 (r,k,l)
  const float* bias = (const float*)d_in[3];  // 4096
  float* out = (float*)d_out;

  unsigned short* Xp = (unsigned short*)d_ws;        // 67MB
  unsigned short* Wp = Xp + (size_t)M_DIM * K_DIM;   // 33.5MB

  prep_kernel<<<2048 + 8192, 256, 0, stream>>>(x, a, b, Xp, Wp);
  gemm_kernel<<<2048, 256, 0, stream>>>(Xp, Wp, bias, out);
}